// Round 1
// baseline (1195.969 us; speedup 1.0000x reference)
//
#include <hip/hip_runtime.h>
#include <hip/hip_bf16.h>

// ---------------------------------------------------------------------------
// GCN forward: 3x (GEMM -> gather/aggregate via CSR) -> mean pool -> FC head.
// CSR built per launch: deg (atomic) -> exclusive scan -> counting-sort place.
// ---------------------------------------------------------------------------

__global__ __launch_bounds__(256) void k_deg(const int* __restrict__ dst,
                                             int* __restrict__ deg, int E) {
    int e = blockIdx.x * 256 + threadIdx.x;
    if (e < E) atomicAdd(&deg[dst[e]], 1);
}

__global__ __launch_bounds__(256) void k_dis(const int* __restrict__ deg,
                                             float* __restrict__ dis, int N) {
    int n = blockIdx.x * 256 + threadIdx.x;
    if (n < N) dis[n] = rsqrtf((float)deg[n] + 1.0f);
}

// Block-wise exclusive scan of deg -> rowptr (block-local), block totals -> partials
__global__ __launch_bounds__(256) void k_scan1(const int* __restrict__ deg,
                                               int* __restrict__ rowptr,
                                               int* __restrict__ partials, int N) {
    __shared__ int sm[256];
    int tid = threadIdx.x;
    int base = blockIdx.x * 1024 + tid * 4;
    int v0 = (base + 0 < N) ? deg[base + 0] : 0;
    int v1 = (base + 1 < N) ? deg[base + 1] : 0;
    int v2 = (base + 2 < N) ? deg[base + 2] : 0;
    int v3 = (base + 3 < N) ? deg[base + 3] : 0;
    int tsum = v0 + v1 + v2 + v3;
    sm[tid] = tsum;
    __syncthreads();
    for (int d = 1; d < 256; d <<= 1) {
        int t = (tid >= d) ? sm[tid - d] : 0;
        __syncthreads();
        sm[tid] += t;
        __syncthreads();
    }
    int excl = sm[tid] - tsum;
    if (tid == 255) partials[blockIdx.x] = sm[255];
    if (base + 0 < N) rowptr[base + 0] = excl;
    if (base + 1 < N) rowptr[base + 1] = excl + v0;
    if (base + 2 < N) rowptr[base + 2] = excl + v0 + v1;
    if (base + 3 < N) rowptr[base + 3] = excl + v0 + v1 + v2;
}

// Single-block exclusive scan of block partials (nb <= 128)
__global__ __launch_bounds__(128) void k_scan2(int* __restrict__ partials, int nb) {
    __shared__ int sm[128];
    int tid = threadIdx.x;
    int v = (tid < nb) ? partials[tid] : 0;
    sm[tid] = v;
    __syncthreads();
    for (int d = 1; d < 128; d <<= 1) {
        int t = (tid >= d) ? sm[tid - d] : 0;
        __syncthreads();
        sm[tid] += t;
        __syncthreads();
    }
    if (tid < nb) partials[tid] = sm[tid] - v;
}

// Add block offsets; also init cursor = rowptr
__global__ __launch_bounds__(256) void k_scan3(int* __restrict__ rowptr,
                                               const int* __restrict__ partials,
                                               int* __restrict__ cursor, int N) {
    int base = blockIdx.x * 1024 + threadIdx.x * 4;
    int off = partials[blockIdx.x];
#pragma unroll
    for (int j = 0; j < 4; ++j) {
        int idx = base + j;
        if (idx < N) {
            int v = rowptr[idx] + off;
            rowptr[idx] = v;
            cursor[idx] = v;
        }
    }
}

// Counting-sort placement: colidx grouped by dst
__global__ __launch_bounds__(256) void k_place(const int* __restrict__ src,
                                               const int* __restrict__ dst,
                                               int* __restrict__ cursor,
                                               int* __restrict__ colidx, int E) {
    int e = blockIdx.x * 256 + threadIdx.x;
    if (e < E) {
        int pos = atomicAdd(&cursor[dst[e]], 1);
        colidx[pos] = src[e];
    }
}

// C[64 rows x 64 cols] per block = A[64 x K] * W[K x 64]. fp32, register tiled 4x4.
// A staged transposed + XOR-swizzled in LDS so both staging writes and compute
// reads are (near) conflict-free; W staged row-major (float4, 2-way = free).
template <int K>
__global__ __launch_bounds__(256) void k_gemm(const float* __restrict__ A,
                                              const float* __restrict__ W,
                                              float* __restrict__ out, int N) {
    __shared__ float As[K * 64];
    __shared__ float Ws[K * 64];
    const int tid = threadIdx.x;
    const int r0 = blockIdx.x * 64;

    {  // stage W
        const float4* Wv = (const float4*)W;
        float4* Wsv = (float4*)Ws;
#pragma unroll
        for (int i = 0; i < (K * 64 / 4) / 256; ++i)
            Wsv[tid + i * 256] = Wv[tid + i * 256];
    }
    {  // stage A, transposed: element (k,row) at As[k*64 + ((row>>2 ^ ((k>>2)&15))<<2) + (row&3)]
#pragma unroll
        for (int i = 0; i < (64 * (K / 4)) / 256; ++i) {
            int idx = tid + i * 256;
            int row = idx / (K / 4);
            int kq = idx % (K / 4);
            int gr = r0 + row;
            float4 a = (gr < N) ? ((const float4*)(A + (size_t)gr * K))[kq]
                                : make_float4(0.f, 0.f, 0.f, 0.f);
            int slot = ((row >> 2) ^ (kq & 15));
            float* p = &As[(kq * 4) * 64 + slot * 4 + (row & 3)];
            p[0 * 64] = a.x;
            p[1 * 64] = a.y;
            p[2 * 64] = a.z;
            p[3 * 64] = a.w;
        }
    }
    __syncthreads();

    const int trow = tid >> 4;  // 0..15 (row quad)
    const int tcol = tid & 15;  // 0..15 (col quad)
    float acc[4][4] = {};
#pragma unroll 4
    for (int k = 0; k < K; ++k) {
        int slot = trow ^ ((k >> 2) & 15);
        float4 a = *(const float4*)&As[k * 64 + slot * 4];
        float4 b = *(const float4*)&Ws[k * 64 + tcol * 4];
        acc[0][0] += a.x * b.x; acc[0][1] += a.x * b.y; acc[0][2] += a.x * b.z; acc[0][3] += a.x * b.w;
        acc[1][0] += a.y * b.x; acc[1][1] += a.y * b.y; acc[1][2] += a.y * b.z; acc[1][3] += a.y * b.w;
        acc[2][0] += a.z * b.x; acc[2][1] += a.z * b.y; acc[2][2] += a.z * b.z; acc[2][3] += a.z * b.w;
        acc[3][0] += a.w * b.x; acc[3][1] += a.w * b.y; acc[3][2] += a.w * b.z; acc[3][3] += a.w * b.w;
    }
#pragma unroll
    for (int i = 0; i < 4; ++i) {
        int gr = r0 + trow * 4 + i;
        if (gr < N) {
            float4 v = make_float4(acc[i][0], acc[i][1], acc[i][2], acc[i][3]);
            *(float4*)&out[(size_t)gr * 64 + tcol * 4] = v;
        }
    }
}

// One wave per node, lane = channel. out[n][c] = act( dis[n]*sum_e dis[s]*h[s][c]
//                                                   + dis[n]^2*h[n][c] + b[c] )
template <int RELU>
__global__ __launch_bounds__(256) void k_agg(const float* __restrict__ h,
                                             const int* __restrict__ rowptr,
                                             const int* __restrict__ deg,
                                             const int* __restrict__ colidx,
                                             const float* __restrict__ dis,
                                             const float* __restrict__ bias,
                                             float* __restrict__ out, int N) {
    int node = blockIdx.x * 4 + (threadIdx.x >> 6);
    int c = threadIdx.x & 63;
    if (node >= N) return;
    int start = rowptr[node];
    int cnt = deg[node];
    float acc = 0.f;
    int i = 0;
    for (; i + 4 <= cnt; i += 4) {
        int s0 = colidx[start + i + 0];
        int s1 = colidx[start + i + 1];
        int s2 = colidx[start + i + 2];
        int s3 = colidx[start + i + 3];
        float w0 = dis[s0], w1 = dis[s1], w2 = dis[s2], w3 = dis[s3];
        float h0 = h[(size_t)s0 * 64 + c];
        float h1 = h[(size_t)s1 * 64 + c];
        float h2 = h[(size_t)s2 * 64 + c];
        float h3 = h[(size_t)s3 * 64 + c];
        acc += w0 * h0 + w1 * h1 + w2 * h2 + w3 * h3;
    }
    for (; i < cnt; ++i) {
        int s = colidx[start + i];
        acc += dis[s] * h[(size_t)s * 64 + c];
    }
    float dn = dis[node];
    float v = dn * acc + dn * dn * h[(size_t)node * 64 + c] + bias[c];
    if (RELU) v = fmaxf(v, 0.f);
    out[(size_t)node * 64 + c] = v;
}

__global__ __launch_bounds__(256) void k_pool(const float* __restrict__ h,
                                              const int* __restrict__ batch,
                                              float* __restrict__ psum,
                                              float* __restrict__ pcnt, int N) {
    int node = blockIdx.x * 4 + (threadIdx.x >> 6);
    int c = threadIdx.x & 63;
    if (node >= N) return;
    int g = batch[node];
    atomicAdd(&psum[g * 64 + c], h[(size_t)node * 64 + c]);
    if (c == 0) atomicAdd(&pcnt[g], 1.0f);
}

__global__ __launch_bounds__(64) void k_head(const float* __restrict__ psum,
                                             const float* __restrict__ pcnt,
                                             const float* __restrict__ Wfc,
                                             const float* __restrict__ bfc,
                                             float* __restrict__ out) {
    __shared__ float p[64];
    int g = blockIdx.x, t = threadIdx.x;
    float cnt = fmaxf(pcnt[g], 1.0f);
    p[t] = psum[g * 64 + t] / cnt;
    __syncthreads();
    if (t < 10) {
        float acc = bfc[t];
#pragma unroll
        for (int hh = 0; hh < 64; ++hh) acc += p[hh] * Wfc[hh * 10 + t];
        out[g * 10 + t] = acc;
    }
}

extern "C" void kernel_launch(void* const* d_in, const int* in_sizes, int n_in,
                              void* d_out, int out_size, void* d_ws, size_t ws_size,
                              hipStream_t stream) {
    const float* x = (const float*)d_in[0];
    const int* eidx = (const int*)d_in[1];
    const int* batch = (const int*)d_in[2];
    const float* W1 = (const float*)d_in[3];
    const float* b1 = (const float*)d_in[4];
    const float* W2 = (const float*)d_in[5];
    const float* b2 = (const float*)d_in[6];
    const float* W3 = (const float*)d_in[7];
    const float* b3 = (const float*)d_in[8];
    const float* Wfc = (const float*)d_in[9];
    const float* bfc = (const float*)d_in[10];
    float* out = (float*)d_out;

    const int N = in_sizes[0] / 128;  // 100000
    const int E = in_sizes[1] / 2;    // 3200000
    const int G = out_size / 10;      // 512

    char* ws = (char*)d_ws;
    size_t off = 0;
    auto alloc = [&](size_t bytes) -> char* {
        char* p = ws + off;
        off = (off + bytes + 511) & ~(size_t)511;
        return p;
    };
    int* deg = (int*)alloc((size_t)N * 4);
    int* rowptr = (int*)alloc((size_t)N * 4);
    int* cursor = (int*)alloc((size_t)N * 4);
    float* dis = (float*)alloc((size_t)N * 4);
    int* partials = (int*)alloc(512);
    int* colidx = (int*)alloc((size_t)E * 4);
    float* hbuf = (float*)alloc((size_t)N * 64 * 4);
    float* obuf = (float*)alloc((size_t)N * 64 * 4);
    float* psum = (float*)alloc((size_t)G * 64 * 4 + (size_t)G * 4);
    float* pcnt = psum + (size_t)G * 64;

    hipMemsetAsync(deg, 0, (size_t)N * 4, stream);
    hipMemsetAsync(psum, 0, (size_t)G * 64 * 4 + (size_t)G * 4, stream);

    const int* esrc = eidx;
    const int* edst = eidx + E;

    k_deg<<<(E + 255) / 256, 256, 0, stream>>>(edst, deg, E);
    k_dis<<<(N + 255) / 256, 256, 0, stream>>>(deg, dis, N);

    int nb = (N + 1023) / 1024;  // 98 <= 128
    k_scan1<<<nb, 256, 0, stream>>>(deg, rowptr, partials, N);
    k_scan2<<<1, 128, 0, stream>>>(partials, nb);
    k_scan3<<<nb, 256, 0, stream>>>(rowptr, partials, cursor, N);
    k_place<<<(E + 255) / 256, 256, 0, stream>>>(esrc, edst, cursor, colidx, E);

    int gblk = (N + 63) / 64;
    k_gemm<128><<<gblk, 256, 0, stream>>>(x, W1, hbuf, N);
    k_agg<1><<<(N + 3) / 4, 256, 0, stream>>>(hbuf, rowptr, deg, colidx, dis, b1, obuf, N);
    k_gemm<64><<<gblk, 256, 0, stream>>>(obuf, W2, hbuf, N);
    k_agg<1><<<(N + 3) / 4, 256, 0, stream>>>(hbuf, rowptr, deg, colidx, dis, b2, obuf, N);
    k_gemm<64><<<gblk, 256, 0, stream>>>(obuf, W3, hbuf, N);
    k_agg<0><<<(N + 3) / 4, 256, 0, stream>>>(hbuf, rowptr, deg, colidx, dis, b3, obuf, N);

    k_pool<<<(N + 3) / 4, 256, 0, stream>>>(obuf, batch, psum, pcnt, N);
    k_head<<<G, 64, 0, stream>>>(psum, pcnt, Wfc, bfc, out);
}

// Round 2
// 646.569 us; speedup vs baseline: 1.8497x; 1.8497x over previous
//
#include <hip/hip_runtime.h>
#include <hip/hip_bf16.h>

// ---------------------------------------------------------------------------
// GCN forward: hierarchical atomic-free CSR build -> 3x (GEMM -> CSR gather
// aggregate) -> run-fused mean pool -> FC head.
// CSR build: bucket = dst>>7 (128 nodes/bucket). LDS histograms -> scans ->
// partition into bucket regions -> per-bucket fine sort (also emits deg,
// rowptr, dis). No global atomics anywhere in the build.
// ---------------------------------------------------------------------------

#define NBLK 256        // partition blocks
#define MAXNB 1024      // max buckets supported (N <= 131072)

// P1: per-block bucket histogram. blockhist[j*NBLK + b] = count of bucket j in block b's chunk.
__global__ __launch_bounds__(256) void k_hist(const int* __restrict__ dst,
                                              int* __restrict__ blockhist,
                                              int E, int chunk, int nb) {
    __shared__ int h[MAXNB];
    int b = blockIdx.x, t = threadIdx.x;
    for (int j = t; j < nb; j += 256) h[j] = 0;
    __syncthreads();
    int lo = b * chunk, hi = min(lo + chunk, E);
    for (int i = lo + t; i < hi; i += 256) atomicAdd(&h[dst[i] >> 7], 1);
    __syncthreads();
    for (int j = t; j < nb; j += 256) blockhist[j * NBLK + b] = h[j];
}

// P2a: per-bucket exclusive scan over blocks (in place); btotal[j] = bucket total.
__global__ __launch_bounds__(256) void k_bscan(int* __restrict__ blockhist,
                                               int* __restrict__ btotal) {
    __shared__ int sm[256];
    int j = blockIdx.x, t = threadIdx.x;
    int v = blockhist[j * NBLK + t];
    sm[t] = v;
    __syncthreads();
    for (int d = 1; d < 256; d <<= 1) {
        int u = (t >= d) ? sm[t - d] : 0;
        __syncthreads();
        sm[t] += u;
        __syncthreads();
    }
    blockhist[j * NBLK + t] = sm[t] - v;
    if (t == 255) btotal[j] = sm[255];
}

// P2b: single-block exclusive scan of bucket totals -> starts[0..nb] (starts[nb] = E).
__global__ __launch_bounds__(256) void k_sscan(const int* __restrict__ btotal,
                                               int* __restrict__ starts, int nb) {
    __shared__ int sm[256];
    int t = threadIdx.x;
    int base = t * 4;
    int v0 = (base + 0 < nb) ? btotal[base + 0] : 0;
    int v1 = (base + 1 < nb) ? btotal[base + 1] : 0;
    int v2 = (base + 2 < nb) ? btotal[base + 2] : 0;
    int v3 = (base + 3 < nb) ? btotal[base + 3] : 0;
    int tsum = v0 + v1 + v2 + v3;
    sm[t] = tsum;
    __syncthreads();
    for (int d = 1; d < 256; d <<= 1) {
        int u = (t >= d) ? sm[t - d] : 0;
        __syncthreads();
        sm[t] += u;
        __syncthreads();
    }
    int excl = sm[t] - tsum;
    if (base + 0 < nb) starts[base + 0] = excl;
    if (base + 1 < nb) starts[base + 1] = excl + v0;
    if (base + 2 < nb) starts[base + 2] = excl + v0 + v1;
    if (base + 3 < nb) starts[base + 3] = excl + v0 + v1 + v2;
    if (t == 255) starts[nb] = sm[255];
}

// P3: partition edges into bucket regions. epart = src | (dst&127)<<17.
__global__ __launch_bounds__(256) void k_part(const int* __restrict__ src,
                                              const int* __restrict__ dst,
                                              const int* __restrict__ blockhist,
                                              const int* __restrict__ starts,
                                              unsigned int* __restrict__ epart,
                                              int E, int chunk, int nb) {
    __shared__ int cur[MAXNB];
    int b = blockIdx.x, t = threadIdx.x;
    for (int j = t; j < nb; j += 256) cur[j] = starts[j] + blockhist[j * NBLK + b];
    __syncthreads();
    int lo = b * chunk, hi = min(lo + chunk, E);
    for (int i = lo + t; i < hi; i += 256) {
        int d = dst[i];
        int j = d >> 7;
        int pos = atomicAdd(&cur[j], 1);
        epart[pos] = (unsigned int)src[i] | ((unsigned int)(d & 127) << 17);
    }
}

// P4: per-bucket fine sort. Emits deg, rowptr, dis, and colidx grouped by dst.
__global__ __launch_bounds__(256) void k_fine(const unsigned int* __restrict__ epart,
                                              const int* __restrict__ starts,
                                              int* __restrict__ deg,
                                              int* __restrict__ rowptr,
                                              float* __restrict__ dis,
                                              int* __restrict__ colidx, int N) {
    __shared__ int cnt[128], sc[128], cur[128];
    int j = blockIdx.x, t = threadIdx.x;
    int n0 = j * 128;
    int nn = min(128, N - n0);
    int s = starts[j], e = starts[j + 1];
    if (t < 128) cnt[t] = 0;
    __syncthreads();
    for (int i = s + t; i < e; i += 256) atomicAdd(&cnt[epart[i] >> 17], 1);
    __syncthreads();
    if (t < 128) sc[t] = cnt[t];
    __syncthreads();
    for (int d = 1; d < 128; d <<= 1) {
        int u = (t < 128 && t >= d) ? sc[t - d] : 0;
        __syncthreads();
        if (t < 128) sc[t] += u;
        __syncthreads();
    }
    if (t < nn) {
        int c = cnt[t];
        int rp = s + sc[t] - c;
        deg[n0 + t] = c;
        rowptr[n0 + t] = rp;
        dis[n0 + t] = rsqrtf((float)c + 1.0f);
        cur[t] = rp;
    }
    __syncthreads();
    for (int i = s + t; i < e; i += 256) {
        unsigned int p = epart[i];
        int pos = atomicAdd(&cur[p >> 17], 1);
        colidx[pos] = (int)(p & 0x1FFFF);
    }
}

// C[64 x 64] per block = A[64 x K] * W[K x 64]. fp32, register tiled 4x4.
template <int K>
__global__ __launch_bounds__(256) void k_gemm(const float* __restrict__ A,
                                              const float* __restrict__ W,
                                              float* __restrict__ out, int N) {
    __shared__ float As[K * 64];
    __shared__ float Ws[K * 64];
    const int tid = threadIdx.x;
    const int r0 = blockIdx.x * 64;

    {
        const float4* Wv = (const float4*)W;
        float4* Wsv = (float4*)Ws;
#pragma unroll
        for (int i = 0; i < (K * 64 / 4) / 256; ++i)
            Wsv[tid + i * 256] = Wv[tid + i * 256];
    }
    {
#pragma unroll
        for (int i = 0; i < (64 * (K / 4)) / 256; ++i) {
            int idx = tid + i * 256;
            int row = idx / (K / 4);
            int kq = idx % (K / 4);
            int gr = r0 + row;
            float4 a = (gr < N) ? ((const float4*)(A + (size_t)gr * K))[kq]
                                : make_float4(0.f, 0.f, 0.f, 0.f);
            int slot = ((row >> 2) ^ (kq & 15));
            float* p = &As[(kq * 4) * 64 + slot * 4 + (row & 3)];
            p[0 * 64] = a.x;
            p[1 * 64] = a.y;
            p[2 * 64] = a.z;
            p[3 * 64] = a.w;
        }
    }
    __syncthreads();

    const int trow = tid >> 4;
    const int tcol = tid & 15;
    float acc[4][4] = {};
#pragma unroll 4
    for (int k = 0; k < K; ++k) {
        int slot = trow ^ ((k >> 2) & 15);
        float4 a = *(const float4*)&As[k * 64 + slot * 4];
        float4 b = *(const float4*)&Ws[k * 64 + tcol * 4];
        acc[0][0] += a.x * b.x; acc[0][1] += a.x * b.y; acc[0][2] += a.x * b.z; acc[0][3] += a.x * b.w;
        acc[1][0] += a.y * b.x; acc[1][1] += a.y * b.y; acc[1][2] += a.y * b.z; acc[1][3] += a.y * b.w;
        acc[2][0] += a.z * b.x; acc[2][1] += a.z * b.y; acc[2][2] += a.z * b.z; acc[2][3] += a.z * b.w;
        acc[3][0] += a.w * b.x; acc[3][1] += a.w * b.y; acc[3][2] += a.w * b.z; acc[3][3] += a.w * b.w;
    }
#pragma unroll
    for (int i = 0; i < 4; ++i) {
        int gr = r0 + trow * 4 + i;
        if (gr < N) {
            float4 v = make_float4(acc[i][0], acc[i][1], acc[i][2], acc[i][3]);
            *(float4*)&out[(size_t)gr * 64 + tcol * 4] = v;
        }
    }
}

// One wave per node, lane = channel.
template <int RELU>
__global__ __launch_bounds__(256) void k_agg(const float* __restrict__ h,
                                             const int* __restrict__ rowptr,
                                             const int* __restrict__ deg,
                                             const int* __restrict__ colidx,
                                             const float* __restrict__ dis,
                                             const float* __restrict__ bias,
                                             float* __restrict__ out, int N) {
    int node = blockIdx.x * 4 + (threadIdx.x >> 6);
    int c = threadIdx.x & 63;
    if (node >= N) return;
    int start = rowptr[node];
    int cnt = deg[node];
    float acc = 0.f;
    int i = 0;
    for (; i + 4 <= cnt; i += 4) {
        int s0 = colidx[start + i + 0];
        int s1 = colidx[start + i + 1];
        int s2 = colidx[start + i + 2];
        int s3 = colidx[start + i + 3];
        float w0 = dis[s0], w1 = dis[s1], w2 = dis[s2], w3 = dis[s3];
        float h0 = h[(size_t)s0 * 64 + c];
        float h1 = h[(size_t)s1 * 64 + c];
        float h2 = h[(size_t)s2 * 64 + c];
        float h3 = h[(size_t)s3 * 64 + c];
        acc += w0 * h0 + w1 * h1 + w2 * h2 + w3 * h3;
    }
    for (; i < cnt; ++i) {
        int s = colidx[start + i];
        acc += dis[s] * h[(size_t)s * 64 + c];
    }
    float dn = dis[node];
    float v = dn * acc + dn * dn * h[(size_t)node * 64 + c] + bias[c];
    if (RELU) v = fmaxf(v, 0.f);
    out[(size_t)node * 64 + c] = v;
}

// Mean pool: batch is sorted -> register-accumulate runs, one atomic per run.
__global__ __launch_bounds__(256) void k_pool(const float* __restrict__ h,
                                              const int* __restrict__ batch,
                                              float* __restrict__ psum,
                                              float* __restrict__ pcnt, int N) {
    int wave = threadIdx.x >> 6;
    int c = threadIdx.x & 63;
    int n0 = blockIdx.x * 64 + wave * 16;
    if (n0 >= N) return;
    int lim = min(n0 + 16, N);
    float acc = 0.f, cnt = 0.f;
    int curg = -1;
    for (int n = n0; n < lim; ++n) {
        int g = batch[n];
        if (g != curg) {
            if (curg >= 0) {
                atomicAdd(&psum[curg * 64 + c], acc);
                if (c == 0) atomicAdd(&pcnt[curg], cnt);
            }
            curg = g;
            acc = 0.f;
            cnt = 0.f;
        }
        acc += h[(size_t)n * 64 + c];
        cnt += 1.f;
    }
    if (curg >= 0) {
        atomicAdd(&psum[curg * 64 + c], acc);
        if (c == 0) atomicAdd(&pcnt[curg], cnt);
    }
}

__global__ __launch_bounds__(64) void k_head(const float* __restrict__ psum,
                                             const float* __restrict__ pcnt,
                                             const float* __restrict__ Wfc,
                                             const float* __restrict__ bfc,
                                             float* __restrict__ out) {
    __shared__ float p[64];
    int g = blockIdx.x, t = threadIdx.x;
    float cnt = fmaxf(pcnt[g], 1.0f);
    p[t] = psum[g * 64 + t] / cnt;
    __syncthreads();
    if (t < 10) {
        float acc = bfc[t];
#pragma unroll
        for (int hh = 0; hh < 64; ++hh) acc += p[hh] * Wfc[hh * 10 + t];
        out[g * 10 + t] = acc;
    }
}

extern "C" void kernel_launch(void* const* d_in, const int* in_sizes, int n_in,
                              void* d_out, int out_size, void* d_ws, size_t ws_size,
                              hipStream_t stream) {
    const float* x = (const float*)d_in[0];
    const int* eidx = (const int*)d_in[1];
    const int* batch = (const int*)d_in[2];
    const float* W1 = (const float*)d_in[3];
    const float* b1 = (const float*)d_in[4];
    const float* W2 = (const float*)d_in[5];
    const float* b2 = (const float*)d_in[6];
    const float* W3 = (const float*)d_in[7];
    const float* b3 = (const float*)d_in[8];
    const float* Wfc = (const float*)d_in[9];
    const float* bfc = (const float*)d_in[10];
    float* out = (float*)d_out;

    const int N = in_sizes[0] / 128;  // 100000
    const int E = in_sizes[1] / 2;    // 3200000
    const int G = out_size / 10;      // 512
    const int NB = (N + 127) / 128;   // 782
    const int chunk = (E + NBLK - 1) / NBLK;

    char* ws = (char*)d_ws;
    size_t off = 0;
    auto alloc = [&](size_t bytes) -> char* {
        char* p = ws + off;
        off = (off + bytes + 511) & ~(size_t)511;
        return p;
    };
    int* deg = (int*)alloc((size_t)N * 4);
    int* rowptr = (int*)alloc((size_t)N * 4);
    float* dis = (float*)alloc((size_t)N * 4);
    int* starts = (int*)alloc((size_t)(MAXNB + 1) * 4);
    int* btotal = (int*)alloc((size_t)MAXNB * 4);
    int* blockhist = (int*)alloc((size_t)NB * NBLK * 4);
    unsigned int* epart = (unsigned int*)alloc((size_t)E * 4);
    int* colidx = (int*)alloc((size_t)E * 4);
    float* hbuf = (float*)alloc((size_t)N * 64 * 4);
    float* obuf = (float*)alloc((size_t)N * 64 * 4);
    float* psum = (float*)alloc((size_t)G * 64 * 4 + (size_t)G * 4);
    float* pcnt = psum + (size_t)G * 64;

    hipMemsetAsync(psum, 0, (size_t)G * 64 * 4 + (size_t)G * 4, stream);

    const int* esrc = eidx;
    const int* edst = eidx + E;

    k_hist<<<NBLK, 256, 0, stream>>>(edst, blockhist, E, chunk, NB);
    k_bscan<<<NB, 256, 0, stream>>>(blockhist, btotal);
    k_sscan<<<1, 256, 0, stream>>>(btotal, starts, NB);
    k_part<<<NBLK, 256, 0, stream>>>(esrc, edst, blockhist, starts, epart, E, chunk, NB);
    k_fine<<<NB, 256, 0, stream>>>(epart, starts, deg, rowptr, dis, colidx, N);

    int gblk = (N + 63) / 64;
    k_gemm<128><<<gblk, 256, 0, stream>>>(x, W1, hbuf, N);
    k_agg<1><<<(N + 3) / 4, 256, 0, stream>>>(hbuf, rowptr, deg, colidx, dis, b1, obuf, N);
    k_gemm<64><<<gblk, 256, 0, stream>>>(obuf, W2, hbuf, N);
    k_agg<1><<<(N + 3) / 4, 256, 0, stream>>>(hbuf, rowptr, deg, colidx, dis, b2, obuf, N);
    k_gemm<64><<<gblk, 256, 0, stream>>>(obuf, W3, hbuf, N);
    k_agg<0><<<(N + 3) / 4, 256, 0, stream>>>(hbuf, rowptr, deg, colidx, dis, b3, obuf, N);

    k_pool<<<(N + 63) / 64, 256, 0, stream>>>(obuf, batch, psum, pcnt, N);
    k_head<<<G, 64, 0, stream>>>(psum, pcnt, Wfc, bfc, out);
}

// Round 3
// 542.996 us; speedup vs baseline: 2.2025x; 1.1907x over previous
//
#include <hip/hip_runtime.h>
#include <hip/hip_bf16.h>

// ---------------------------------------------------------------------------
// GCN forward: hierarchical atomic-free CSR build -> 3x (GEMM w/ fused
// dis-scale + bf16 store -> CSR gather aggregate) -> run-fused mean pool ->
// FC head.
// Key trick: aggregation is linear, so GEMM epilogue stores hs = dis[n]*h[n]
// in bf16. agg[n] = dis[n] * (sum_{s in N(n)} hs[s] + hs[n]) + b.
// Halves gather working set (12.8 MB) + bytes/edge, drops dis[src] gather.
// ---------------------------------------------------------------------------

#define NBLK 256        // partition blocks
#define MAXNB 1024      // max buckets supported (N <= 131072)

__device__ __forceinline__ float bf2f(unsigned short v) {
    return __uint_as_float(((unsigned int)v) << 16);
}
__device__ __forceinline__ unsigned short f2bf(float x) {
    __hip_bfloat16 b = __float2bfloat16(x);  // round-to-nearest
    return *(unsigned short*)&b;
}

// P1: per-block bucket histogram.
__global__ __launch_bounds__(256) void k_hist(const int* __restrict__ dst,
                                              int* __restrict__ blockhist,
                                              int E, int chunk, int nb) {
    __shared__ int h[MAXNB];
    int b = blockIdx.x, t = threadIdx.x;
    for (int j = t; j < nb; j += 256) h[j] = 0;
    __syncthreads();
    int lo = b * chunk, hi = min(lo + chunk, E);
    for (int i = lo + t; i < hi; i += 256) atomicAdd(&h[dst[i] >> 7], 1);
    __syncthreads();
    for (int j = t; j < nb; j += 256) blockhist[j * NBLK + b] = h[j];
}

// P2a: per-bucket exclusive scan over blocks (in place); btotal[j] = total.
__global__ __launch_bounds__(256) void k_bscan(int* __restrict__ blockhist,
                                               int* __restrict__ btotal) {
    __shared__ int sm[256];
    int j = blockIdx.x, t = threadIdx.x;
    int v = blockhist[j * NBLK + t];
    sm[t] = v;
    __syncthreads();
    for (int d = 1; d < 256; d <<= 1) {
        int u = (t >= d) ? sm[t - d] : 0;
        __syncthreads();
        sm[t] += u;
        __syncthreads();
    }
    blockhist[j * NBLK + t] = sm[t] - v;
    if (t == 255) btotal[j] = sm[255];
}

// P2b: single-block exclusive scan of bucket totals -> starts[0..nb].
__global__ __launch_bounds__(256) void k_sscan(const int* __restrict__ btotal,
                                               int* __restrict__ starts, int nb) {
    __shared__ int sm[256];
    int t = threadIdx.x;
    int base = t * 4;
    int v0 = (base + 0 < nb) ? btotal[base + 0] : 0;
    int v1 = (base + 1 < nb) ? btotal[base + 1] : 0;
    int v2 = (base + 2 < nb) ? btotal[base + 2] : 0;
    int v3 = (base + 3 < nb) ? btotal[base + 3] : 0;
    int tsum = v0 + v1 + v2 + v3;
    sm[t] = tsum;
    __syncthreads();
    for (int d = 1; d < 256; d <<= 1) {
        int u = (t >= d) ? sm[t - d] : 0;
        __syncthreads();
        sm[t] += u;
        __syncthreads();
    }
    int excl = sm[t] - tsum;
    if (base + 0 < nb) starts[base + 0] = excl;
    if (base + 1 < nb) starts[base + 1] = excl + v0;
    if (base + 2 < nb) starts[base + 2] = excl + v0 + v1;
    if (base + 3 < nb) starts[base + 3] = excl + v0 + v1 + v2;
    if (t == 255) starts[nb] = sm[255];
}

// P3: partition edges into bucket regions. epart = src | (dst&127)<<17.
__global__ __launch_bounds__(256) void k_part(const int* __restrict__ src,
                                              const int* __restrict__ dst,
                                              const int* __restrict__ blockhist,
                                              const int* __restrict__ starts,
                                              unsigned int* __restrict__ epart,
                                              int E, int chunk, int nb) {
    __shared__ int cur[MAXNB];
    int b = blockIdx.x, t = threadIdx.x;
    for (int j = t; j < nb; j += 256) cur[j] = starts[j] + blockhist[j * NBLK + b];
    __syncthreads();
    int lo = b * chunk, hi = min(lo + chunk, E);
    for (int i = lo + t; i < hi; i += 256) {
        int d = dst[i];
        int j = d >> 7;
        int pos = atomicAdd(&cur[j], 1);
        epart[pos] = (unsigned int)src[i] | ((unsigned int)(d & 127) << 17);
    }
}

// P4: per-bucket fine sort. Emits deg, rowptr, dis, and colidx grouped by dst.
__global__ __launch_bounds__(256) void k_fine(const unsigned int* __restrict__ epart,
                                              const int* __restrict__ starts,
                                              int* __restrict__ deg,
                                              int* __restrict__ rowptr,
                                              float* __restrict__ dis,
                                              int* __restrict__ colidx, int N) {
    __shared__ int cnt[128], sc[128], cur[128];
    int j = blockIdx.x, t = threadIdx.x;
    int n0 = j * 128;
    int nn = min(128, N - n0);
    int s = starts[j], e = starts[j + 1];
    if (t < 128) cnt[t] = 0;
    __syncthreads();
    for (int i = s + t; i < e; i += 256) atomicAdd(&cnt[epart[i] >> 17], 1);
    __syncthreads();
    if (t < 128) sc[t] = cnt[t];
    __syncthreads();
    for (int d = 1; d < 128; d <<= 1) {
        int u = (t < 128 && t >= d) ? sc[t - d] : 0;
        __syncthreads();
        if (t < 128) sc[t] += u;
        __syncthreads();
    }
    if (t < nn) {
        int c = cnt[t];
        int rp = s + sc[t] - c;
        deg[n0 + t] = c;
        rowptr[n0 + t] = rp;
        dis[n0 + t] = rsqrtf((float)c + 1.0f);
        cur[t] = rp;
    }
    __syncthreads();
    for (int i = s + t; i < e; i += 256) {
        unsigned int p = epart[i];
        int pos = atomicAdd(&cur[p >> 17], 1);
        colidx[pos] = (int)(p & 0x1FFFF);
    }
}

// C[64 x 64] per block = A[64 x K] * W[K x 64]. fp32 accumulate, epilogue
// scales row by dis[row] and stores bf16.
template <int K>
__global__ __launch_bounds__(256) void k_gemm(const float* __restrict__ A,
                                              const float* __restrict__ W,
                                              const float* __restrict__ dis,
                                              unsigned short* __restrict__ hs,
                                              int N) {
    __shared__ float As[K * 64];
    __shared__ float Ws[K * 64];
    const int tid = threadIdx.x;
    const int r0 = blockIdx.x * 64;

    {
        const float4* Wv = (const float4*)W;
        float4* Wsv = (float4*)Ws;
#pragma unroll
        for (int i = 0; i < (K * 64 / 4) / 256; ++i)
            Wsv[tid + i * 256] = Wv[tid + i * 256];
    }
    {
#pragma unroll
        for (int i = 0; i < (64 * (K / 4)) / 256; ++i) {
            int idx = tid + i * 256;
            int row = idx / (K / 4);
            int kq = idx % (K / 4);
            int gr = r0 + row;
            float4 a = (gr < N) ? ((const float4*)(A + (size_t)gr * K))[kq]
                                : make_float4(0.f, 0.f, 0.f, 0.f);
            int slot = ((row >> 2) ^ (kq & 15));
            float* p = &As[(kq * 4) * 64 + slot * 4 + (row & 3)];
            p[0 * 64] = a.x;
            p[1 * 64] = a.y;
            p[2 * 64] = a.z;
            p[3 * 64] = a.w;
        }
    }
    __syncthreads();

    const int trow = tid >> 4;
    const int tcol = tid & 15;
    float acc[4][4] = {};
#pragma unroll 4
    for (int k = 0; k < K; ++k) {
        int slot = trow ^ ((k >> 2) & 15);
        float4 a = *(const float4*)&As[k * 64 + slot * 4];
        float4 b = *(const float4*)&Ws[k * 64 + tcol * 4];
        acc[0][0] += a.x * b.x; acc[0][1] += a.x * b.y; acc[0][2] += a.x * b.z; acc[0][3] += a.x * b.w;
        acc[1][0] += a.y * b.x; acc[1][1] += a.y * b.y; acc[1][2] += a.y * b.z; acc[1][3] += a.y * b.w;
        acc[2][0] += a.z * b.x; acc[2][1] += a.z * b.y; acc[2][2] += a.z * b.z; acc[2][3] += a.z * b.w;
        acc[3][0] += a.w * b.x; acc[3][1] += a.w * b.y; acc[3][2] += a.w * b.z; acc[3][3] += a.w * b.w;
    }
#pragma unroll
    for (int i = 0; i < 4; ++i) {
        int gr = r0 + trow * 4 + i;
        if (gr < N) {
            float dn = dis[gr];
            ushort4 v;
            v.x = f2bf(acc[i][0] * dn);
            v.y = f2bf(acc[i][1] * dn);
            v.z = f2bf(acc[i][2] * dn);
            v.w = f2bf(acc[i][3] * dn);
            *(ushort4*)&hs[(size_t)gr * 64 + tcol * 4] = v;
        }
    }
}

// One wave per node, lane = channel. hs is bf16, pre-scaled by dis[src].
// out[n][c] = act( dis[n] * (sum_{s} hs[s][c] + hs[n][c]) + b[c] )  (fp32)
template <int RELU>
__global__ __launch_bounds__(256) void k_agg(const unsigned short* __restrict__ hs,
                                             const int* __restrict__ rowptr,
                                             const int* __restrict__ deg,
                                             const int* __restrict__ colidx,
                                             const float* __restrict__ dis,
                                             const float* __restrict__ bias,
                                             float* __restrict__ out, int N) {
    int node = blockIdx.x * 4 + (threadIdx.x >> 6);
    int c = threadIdx.x & 63;
    if (node >= N) return;
    int start = rowptr[node];
    int cnt = deg[node];
    float acc = bf2f(hs[(size_t)node * 64 + c]);  // self-loop term
    int i = 0;
    for (; i + 8 <= cnt; i += 8) {
        int s0 = colidx[start + i + 0];
        int s1 = colidx[start + i + 1];
        int s2 = colidx[start + i + 2];
        int s3 = colidx[start + i + 3];
        int s4 = colidx[start + i + 4];
        int s5 = colidx[start + i + 5];
        int s6 = colidx[start + i + 6];
        int s7 = colidx[start + i + 7];
        unsigned short v0 = hs[(size_t)s0 * 64 + c];
        unsigned short v1 = hs[(size_t)s1 * 64 + c];
        unsigned short v2 = hs[(size_t)s2 * 64 + c];
        unsigned short v3 = hs[(size_t)s3 * 64 + c];
        unsigned short v4 = hs[(size_t)s4 * 64 + c];
        unsigned short v5 = hs[(size_t)s5 * 64 + c];
        unsigned short v6 = hs[(size_t)s6 * 64 + c];
        unsigned short v7 = hs[(size_t)s7 * 64 + c];
        acc += bf2f(v0) + bf2f(v1) + bf2f(v2) + bf2f(v3)
             + bf2f(v4) + bf2f(v5) + bf2f(v6) + bf2f(v7);
    }
    for (; i < cnt; ++i) {
        int s = colidx[start + i];
        acc += bf2f(hs[(size_t)s * 64 + c]);
    }
    float v = dis[node] * acc + bias[c];
    if (RELU) v = fmaxf(v, 0.f);
    out[(size_t)node * 64 + c] = v;
}

// Mean pool: batch is sorted -> register-accumulate runs, one atomic per run.
__global__ __launch_bounds__(256) void k_pool(const float* __restrict__ h,
                                              const int* __restrict__ batch,
                                              float* __restrict__ psum,
                                              float* __restrict__ pcnt, int N) {
    int wave = threadIdx.x >> 6;
    int c = threadIdx.x & 63;
    int n0 = blockIdx.x * 64 + wave * 16;
    if (n0 >= N) return;
    int lim = min(n0 + 16, N);
    float acc = 0.f, cnt = 0.f;
    int curg = -1;
    for (int n = n0; n < lim; ++n) {
        int g = batch[n];
        if (g != curg) {
            if (curg >= 0) {
                atomicAdd(&psum[curg * 64 + c], acc);
                if (c == 0) atomicAdd(&pcnt[curg], cnt);
            }
            curg = g;
            acc = 0.f;
            cnt = 0.f;
        }
        acc += h[(size_t)n * 64 + c];
        cnt += 1.f;
    }
    if (curg >= 0) {
        atomicAdd(&psum[curg * 64 + c], acc);
        if (c == 0) atomicAdd(&pcnt[curg], cnt);
    }
}

__global__ __launch_bounds__(64) void k_head(const float* __restrict__ psum,
                                             const float* __restrict__ pcnt,
                                             const float* __restrict__ Wfc,
                                             const float* __restrict__ bfc,
                                             float* __restrict__ out) {
    __shared__ float p[64];
    int g = blockIdx.x, t = threadIdx.x;
    float cnt = fmaxf(pcnt[g], 1.0f);
    p[t] = psum[g * 64 + t] / cnt;
    __syncthreads();
    if (t < 10) {
        float acc = bfc[t];
#pragma unroll
        for (int hh = 0; hh < 64; ++hh) acc += p[hh] * Wfc[hh * 10 + t];
        out[g * 10 + t] = acc;
    }
}

extern "C" void kernel_launch(void* const* d_in, const int* in_sizes, int n_in,
                              void* d_out, int out_size, void* d_ws, size_t ws_size,
                              hipStream_t stream) {
    const float* x = (const float*)d_in[0];
    const int* eidx = (const int*)d_in[1];
    const int* batch = (const int*)d_in[2];
    const float* W1 = (const float*)d_in[3];
    const float* b1 = (const float*)d_in[4];
    const float* W2 = (const float*)d_in[5];
    const float* b2 = (const float*)d_in[6];
    const float* W3 = (const float*)d_in[7];
    const float* b3 = (const float*)d_in[8];
    const float* Wfc = (const float*)d_in[9];
    const float* bfc = (const float*)d_in[10];
    float* out = (float*)d_out;

    const int N = in_sizes[0] / 128;  // 100000
    const int E = in_sizes[1] / 2;    // 3200000
    const int G = out_size / 10;      // 512
    const int NB = (N + 127) / 128;   // 782
    const int chunk = (E + NBLK - 1) / NBLK;

    char* ws = (char*)d_ws;
    size_t off = 0;
    auto alloc = [&](size_t bytes) -> char* {
        char* p = ws + off;
        off = (off + bytes + 511) & ~(size_t)511;
        return p;
    };
    int* deg = (int*)alloc((size_t)N * 4);
    int* rowptr = (int*)alloc((size_t)N * 4);
    float* dis = (float*)alloc((size_t)N * 4);
    int* starts = (int*)alloc((size_t)(MAXNB + 1) * 4);
    int* btotal = (int*)alloc((size_t)MAXNB * 4);
    int* blockhist = (int*)alloc((size_t)NB * NBLK * 4);
    unsigned int* epart = (unsigned int*)alloc((size_t)E * 4);
    int* colidx = (int*)alloc((size_t)E * 4);
    unsigned short* hsb = (unsigned short*)alloc((size_t)N * 64 * 2);  // bf16
    float* obuf = (float*)alloc((size_t)N * 64 * 4);
    float* psum = (float*)alloc((size_t)G * 64 * 4 + (size_t)G * 4);
    float* pcnt = psum + (size_t)G * 64;

    hipMemsetAsync(psum, 0, (size_t)G * 64 * 4 + (size_t)G * 4, stream);

    const int* esrc = eidx;
    const int* edst = eidx + E;

    k_hist<<<NBLK, 256, 0, stream>>>(edst, blockhist, E, chunk, NB);
    k_bscan<<<NB, 256, 0, stream>>>(blockhist, btotal);
    k_sscan<<<1, 256, 0, stream>>>(btotal, starts, NB);
    k_part<<<NBLK, 256, 0, stream>>>(esrc, edst, blockhist, starts, epart, E, chunk, NB);
    k_fine<<<NB, 256, 0, stream>>>(epart, starts, deg, rowptr, dis, colidx, N);

    int gblk = (N + 63) / 64;
    k_gemm<128><<<gblk, 256, 0, stream>>>(x, W1, dis, hsb, N);
    k_agg<1><<<(N + 3) / 4, 256, 0, stream>>>(hsb, rowptr, deg, colidx, dis, b1, obuf, N);
    k_gemm<64><<<gblk, 256, 0, stream>>>(obuf, W2, dis, hsb, N);
    k_agg<1><<<(N + 3) / 4, 256, 0, stream>>>(hsb, rowptr, deg, colidx, dis, b2, obuf, N);
    k_gemm<64><<<gblk, 256, 0, stream>>>(obuf, W3, dis, hsb, N);
    k_agg<0><<<(N + 3) / 4, 256, 0, stream>>>(hsb, rowptr, deg, colidx, dis, b3, obuf, N);

    k_pool<<<(N + 63) / 64, 256, 0, stream>>>(obuf, batch, psum, pcnt, N);
    k_head<<<G, 64, 0, stream>>>(psum, pcnt, Wfc, bfc, out);
}

// Round 4
// 450.429 us; speedup vs baseline: 2.6552x; 1.2055x over previous
//
#include <hip/hip_runtime.h>
#include <hip/hip_bf16.h>

// ---------------------------------------------------------------------------
// GCN forward: hierarchical atomic-free CSR build -> 3x (GEMM w/ fused
// dis-scale + bf16 store -> CSR gather aggregate) -> run-fused mean pool ->
// FC head.
// hs = dis[n]*h[n] in bf16; agg[n] = dis[n]*(sum hs[s] + hs[n]) + b.
// k_agg lane map: lane = eslot(0..3) x chquad(0..15); ushort4 gathers move
// 4 edges per VMEM instruction; shfl_xor butterfly merges edge slots.
// ---------------------------------------------------------------------------

#define NBLK 256        // partition blocks
#define MAXNB 1024      // max buckets supported (N <= 131072)
#define FCAP 4608       // LDS edge-staging capacity in k_fine

__device__ __forceinline__ float bf2f(unsigned short v) {
    return __uint_as_float(((unsigned int)v) << 16);
}
__device__ __forceinline__ unsigned short f2bf(float x) {
    __hip_bfloat16 b = __float2bfloat16(x);  // round-to-nearest
    return *(unsigned short*)&b;
}
__device__ __forceinline__ float4 bf4(ushort4 v) {
    return make_float4(bf2f(v.x), bf2f(v.y), bf2f(v.z), bf2f(v.w));
}

// P1: per-block bucket histogram (int4-vectorized edge reads).
__global__ __launch_bounds__(256) void k_hist(const int* __restrict__ dst,
                                              int* __restrict__ blockhist,
                                              int E, int chunk, int nb) {
    __shared__ int h[MAXNB];
    int b = blockIdx.x, t = threadIdx.x;
    for (int j = t; j < nb; j += 256) h[j] = 0;
    __syncthreads();
    int lo = b * chunk, hi = min(lo + chunk, E);
    int m = hi - lo;
    int nv = m >> 2;
    const int4* d4 = (const int4*)(dst + lo);
    for (int i = t; i < nv; i += 256) {
        int4 v = d4[i];
        atomicAdd(&h[v.x >> 7], 1);
        atomicAdd(&h[v.y >> 7], 1);
        atomicAdd(&h[v.z >> 7], 1);
        atomicAdd(&h[v.w >> 7], 1);
    }
    for (int i = lo + (nv << 2) + t; i < hi; i += 256) atomicAdd(&h[dst[i] >> 7], 1);
    __syncthreads();
    for (int j = t; j < nb; j += 256) blockhist[j * NBLK + b] = h[j];
}

// P2a: per-bucket exclusive scan over blocks (in place); btotal[j] = total.
__global__ __launch_bounds__(256) void k_bscan(int* __restrict__ blockhist,
                                               int* __restrict__ btotal) {
    __shared__ int sm[256];
    int j = blockIdx.x, t = threadIdx.x;
    int v = blockhist[j * NBLK + t];
    sm[t] = v;
    __syncthreads();
    for (int d = 1; d < 256; d <<= 1) {
        int u = (t >= d) ? sm[t - d] : 0;
        __syncthreads();
        sm[t] += u;
        __syncthreads();
    }
    blockhist[j * NBLK + t] = sm[t] - v;
    if (t == 255) btotal[j] = sm[255];
}

// P2b: single-block exclusive scan of bucket totals -> starts[0..nb].
__global__ __launch_bounds__(256) void k_sscan(const int* __restrict__ btotal,
                                               int* __restrict__ starts, int nb) {
    __shared__ int sm[256];
    int t = threadIdx.x;
    int base = t * 4;
    int v0 = (base + 0 < nb) ? btotal[base + 0] : 0;
    int v1 = (base + 1 < nb) ? btotal[base + 1] : 0;
    int v2 = (base + 2 < nb) ? btotal[base + 2] : 0;
    int v3 = (base + 3 < nb) ? btotal[base + 3] : 0;
    int tsum = v0 + v1 + v2 + v3;
    sm[t] = tsum;
    __syncthreads();
    for (int d = 1; d < 256; d <<= 1) {
        int u = (t >= d) ? sm[t - d] : 0;
        __syncthreads();
        sm[t] += u;
        __syncthreads();
    }
    int excl = sm[t] - tsum;
    if (base + 0 < nb) starts[base + 0] = excl;
    if (base + 1 < nb) starts[base + 1] = excl + v0;
    if (base + 2 < nb) starts[base + 2] = excl + v0 + v1;
    if (base + 3 < nb) starts[base + 3] = excl + v0 + v1 + v2;
    if (t == 255) starts[nb] = sm[255];
}

// P3: partition edges into bucket regions. epart = src | (dst&127)<<17.
__global__ __launch_bounds__(256) void k_part(const int* __restrict__ src,
                                              const int* __restrict__ dst,
                                              const int* __restrict__ blockhist,
                                              const int* __restrict__ starts,
                                              unsigned int* __restrict__ epart,
                                              int E, int chunk, int nb) {
    __shared__ int cur[MAXNB];
    int b = blockIdx.x, t = threadIdx.x;
    for (int j = t; j < nb; j += 256) cur[j] = starts[j] + blockhist[j * NBLK + b];
    __syncthreads();
    int lo = b * chunk, hi = min(lo + chunk, E);
    int m = hi - lo;
    int nv = m >> 2;
    const int4* d4 = (const int4*)(dst + lo);
    const int4* s4 = (const int4*)(src + lo);
    for (int i = t; i < nv; i += 256) {
        int4 d = d4[i];
        int4 s = s4[i];
        int p;
        p = atomicAdd(&cur[d.x >> 7], 1); epart[p] = (unsigned int)s.x | ((unsigned int)(d.x & 127) << 17);
        p = atomicAdd(&cur[d.y >> 7], 1); epart[p] = (unsigned int)s.y | ((unsigned int)(d.y & 127) << 17);
        p = atomicAdd(&cur[d.z >> 7], 1); epart[p] = (unsigned int)s.z | ((unsigned int)(d.z & 127) << 17);
        p = atomicAdd(&cur[d.w >> 7], 1); epart[p] = (unsigned int)s.w | ((unsigned int)(d.w & 127) << 17);
    }
    for (int i = lo + (nv << 2) + t; i < hi; i += 256) {
        int d = dst[i];
        int pos = atomicAdd(&cur[d >> 7], 1);
        epart[pos] = (unsigned int)src[i] | ((unsigned int)(d & 127) << 17);
    }
}

// P4: per-bucket fine sort, edges staged in LDS. Emits deg/rowptr/dis/colidx.
__global__ __launch_bounds__(256) void k_fine(const unsigned int* __restrict__ epart,
                                              const int* __restrict__ starts,
                                              int* __restrict__ deg,
                                              int* __restrict__ rowptr,
                                              float* __restrict__ dis,
                                              int* __restrict__ colidx, int N) {
    __shared__ unsigned int eb[FCAP];
    __shared__ int cnt[128], sc[128], cur[128];
    int j = blockIdx.x, t = threadIdx.x;
    int n0 = j * 128;
    int nn = min(128, N - n0);
    int s = starts[j], e = starts[j + 1];
    int m = e - s;
    if (t < 128) cnt[t] = 0;
    __syncthreads();
    for (int i = t; i < m; i += 256) {
        unsigned int p = epart[s + i];
        if (i < FCAP) eb[i] = p;
        atomicAdd(&cnt[p >> 17], 1);
    }
    __syncthreads();
    if (t < 128) sc[t] = cnt[t];
    __syncthreads();
    for (int d = 1; d < 128; d <<= 1) {
        int u = (t < 128 && t >= d) ? sc[t - d] : 0;
        __syncthreads();
        if (t < 128) sc[t] += u;
        __syncthreads();
    }
    if (t < nn) {
        int c = cnt[t];
        int rp = s + sc[t] - c;
        deg[n0 + t] = c;
        rowptr[n0 + t] = rp;
        dis[n0 + t] = rsqrtf((float)c + 1.0f);
        cur[t] = rp;
    }
    __syncthreads();
    for (int i = t; i < m; i += 256) {
        unsigned int p = (i < FCAP) ? eb[i] : epart[s + i];
        int pos = atomicAdd(&cur[p >> 17], 1);
        colidx[pos] = (int)(p & 0x1FFFF);
    }
}

// C[64 x 64] per block = A[64 x K] * W[K x 64]. fp32 accumulate, epilogue
// scales row by dis[row] and stores bf16.
template <int K>
__global__ __launch_bounds__(256) void k_gemm(const float* __restrict__ A,
                                              const float* __restrict__ W,
                                              const float* __restrict__ dis,
                                              unsigned short* __restrict__ hs,
                                              int N) {
    __shared__ float As[K * 64];
    __shared__ float Ws[K * 64];
    const int tid = threadIdx.x;
    const int r0 = blockIdx.x * 64;

    {
        const float4* Wv = (const float4*)W;
        float4* Wsv = (float4*)Ws;
#pragma unroll
        for (int i = 0; i < (K * 64 / 4) / 256; ++i)
            Wsv[tid + i * 256] = Wv[tid + i * 256];
    }
    {
#pragma unroll
        for (int i = 0; i < (64 * (K / 4)) / 256; ++i) {
            int idx = tid + i * 256;
            int row = idx / (K / 4);
            int kq = idx % (K / 4);
            int gr = r0 + row;
            float4 a = (gr < N) ? ((const float4*)(A + (size_t)gr * K))[kq]
                                : make_float4(0.f, 0.f, 0.f, 0.f);
            int slot = ((row >> 2) ^ (kq & 15));
            float* p = &As[(kq * 4) * 64 + slot * 4 + (row & 3)];
            p[0 * 64] = a.x;
            p[1 * 64] = a.y;
            p[2 * 64] = a.z;
            p[3 * 64] = a.w;
        }
    }
    __syncthreads();

    const int trow = tid >> 4;
    const int tcol = tid & 15;
    float acc[4][4] = {};
#pragma unroll 4
    for (int k = 0; k < K; ++k) {
        int slot = trow ^ ((k >> 2) & 15);
        float4 a = *(const float4*)&As[k * 64 + slot * 4];
        float4 b = *(const float4*)&Ws[k * 64 + tcol * 4];
        acc[0][0] += a.x * b.x; acc[0][1] += a.x * b.y; acc[0][2] += a.x * b.z; acc[0][3] += a.x * b.w;
        acc[1][0] += a.y * b.x; acc[1][1] += a.y * b.y; acc[1][2] += a.y * b.z; acc[1][3] += a.y * b.w;
        acc[2][0] += a.z * b.x; acc[2][1] += a.z * b.y; acc[2][2] += a.z * b.z; acc[2][3] += a.z * b.w;
        acc[3][0] += a.w * b.x; acc[3][1] += a.w * b.y; acc[3][2] += a.w * b.z; acc[3][3] += a.w * b.w;
    }
#pragma unroll
    for (int i = 0; i < 4; ++i) {
        int gr = r0 + trow * 4 + i;
        if (gr < N) {
            float dn = dis[gr];
            ushort4 v;
            v.x = f2bf(acc[i][0] * dn);
            v.y = f2bf(acc[i][1] * dn);
            v.z = f2bf(acc[i][2] * dn);
            v.w = f2bf(acc[i][3] * dn);
            *(ushort4*)&hs[(size_t)gr * 64 + tcol * 4] = v;
        }
    }
}

// One wave per node. lane = eslot(0..3) x chquad(0..15). Each gather instr
// moves 4 edges x 4 channels (ushort4/lane). Butterfly-reduce edge slots.
template <int RELU>
__global__ __launch_bounds__(256) void k_agg(const unsigned short* __restrict__ hs,
                                             const int* __restrict__ rowptr,
                                             const int* __restrict__ deg,
                                             const int* __restrict__ colidx,
                                             const float* __restrict__ dis,
                                             const float* __restrict__ bias,
                                             float* __restrict__ out, int N) {
    int node = blockIdx.x * 4 + (threadIdx.x >> 6);
    if (node >= N) return;
    int lane = threadIdx.x & 63;
    int eslot = lane >> 4;   // 0..3: which edge of the quad
    int cq = lane & 15;      // channel quad: channels 4*cq..4*cq+3

    int start = rowptr[node];
    int cnt = deg[node];
    float4 acc = make_float4(0.f, 0.f, 0.f, 0.f);

    int i = 0;
    for (; i + 16 <= cnt; i += 16) {
        int s0 = colidx[start + i + 0 + eslot];
        int s1 = colidx[start + i + 4 + eslot];
        int s2 = colidx[start + i + 8 + eslot];
        int s3 = colidx[start + i + 12 + eslot];
        ushort4 a0 = *(const ushort4*)&hs[(size_t)s0 * 64 + cq * 4];
        ushort4 a1 = *(const ushort4*)&hs[(size_t)s1 * 64 + cq * 4];
        ushort4 a2 = *(const ushort4*)&hs[(size_t)s2 * 64 + cq * 4];
        ushort4 a3 = *(const ushort4*)&hs[(size_t)s3 * 64 + cq * 4];
        float4 f0 = bf4(a0), f1 = bf4(a1), f2 = bf4(a2), f3 = bf4(a3);
        acc.x += f0.x + f1.x + f2.x + f3.x;
        acc.y += f0.y + f1.y + f2.y + f3.y;
        acc.z += f0.z + f1.z + f2.z + f3.z;
        acc.w += f0.w + f1.w + f2.w + f3.w;
    }
    for (; i < cnt; i += 4) {
        int idx = i + eslot;
        if (idx < cnt) {
            int s = colidx[start + idx];
            ushort4 a = *(const ushort4*)&hs[(size_t)s * 64 + cq * 4];
            float4 f = bf4(a);
            acc.x += f.x; acc.y += f.y; acc.z += f.z; acc.w += f.w;
        }
    }

    // reduce across the 4 edge slots (lanes l, l^16, l^32, l^48)
    acc.x += __shfl_xor(acc.x, 16, 64);
    acc.y += __shfl_xor(acc.y, 16, 64);
    acc.z += __shfl_xor(acc.z, 16, 64);
    acc.w += __shfl_xor(acc.w, 16, 64);
    acc.x += __shfl_xor(acc.x, 32, 64);
    acc.y += __shfl_xor(acc.y, 32, 64);
    acc.z += __shfl_xor(acc.z, 32, 64);
    acc.w += __shfl_xor(acc.w, 32, 64);

    if (eslot == 0) {
        ushort4 sv = *(const ushort4*)&hs[(size_t)node * 64 + cq * 4];
        float4 sf = bf4(sv);
        float dn = dis[node];
        float4 bb = *(const float4*)&bias[cq * 4];
        float4 v;
        v.x = dn * (acc.x + sf.x) + bb.x;
        v.y = dn * (acc.y + sf.y) + bb.y;
        v.z = dn * (acc.z + sf.z) + bb.z;
        v.w = dn * (acc.w + sf.w) + bb.w;
        if (RELU) {
            v.x = fmaxf(v.x, 0.f); v.y = fmaxf(v.y, 0.f);
            v.z = fmaxf(v.z, 0.f); v.w = fmaxf(v.w, 0.f);
        }
        *(float4*)&out[(size_t)node * 64 + cq * 4] = v;
    }
}

// Mean pool: batch is sorted -> register-accumulate runs, one atomic per run.
__global__ __launch_bounds__(256) void k_pool(const float* __restrict__ h,
                                              const int* __restrict__ batch,
                                              float* __restrict__ psum,
                                              float* __restrict__ pcnt, int N) {
    int wave = threadIdx.x >> 6;
    int c = threadIdx.x & 63;
    int n0 = blockIdx.x * 64 + wave * 16;
    if (n0 >= N) return;
    int lim = min(n0 + 16, N);
    float acc = 0.f, cnt = 0.f;
    int curg = -1;
    for (int n = n0; n < lim; ++n) {
        int g = batch[n];
        if (g != curg) {
            if (curg >= 0) {
                atomicAdd(&psum[curg * 64 + c], acc);
                if (c == 0) atomicAdd(&pcnt[curg], cnt);
            }
            curg = g;
            acc = 0.f;
            cnt = 0.f;
        }
        acc += h[(size_t)n * 64 + c];
        cnt += 1.f;
    }
    if (curg >= 0) {
        atomicAdd(&psum[curg * 64 + c], acc);
        if (c == 0) atomicAdd(&pcnt[curg], cnt);
    }
}

__global__ __launch_bounds__(64) void k_head(const float* __restrict__ psum,
                                             const float* __restrict__ pcnt,
                                             const float* __restrict__ Wfc,
                                             const float* __restrict__ bfc,
                                             float* __restrict__ out) {
    __shared__ float p[64];
    int g = blockIdx.x, t = threadIdx.x;
    float cnt = fmaxf(pcnt[g], 1.0f);
    p[t] = psum[g * 64 + t] / cnt;
    __syncthreads();
    if (t < 10) {
        float acc = bfc[t];
#pragma unroll
        for (int hh = 0; hh < 64; ++hh) acc += p[hh] * Wfc[hh * 10 + t];
        out[g * 10 + t] = acc;
    }
}

extern "C" void kernel_launch(void* const* d_in, const int* in_sizes, int n_in,
                              void* d_out, int out_size, void* d_ws, size_t ws_size,
                              hipStream_t stream) {
    const float* x = (const float*)d_in[0];
    const int* eidx = (const int*)d_in[1];
    const int* batch = (const int*)d_in[2];
    const float* W1 = (const float*)d_in[3];
    const float* b1 = (const float*)d_in[4];
    const float* W2 = (const float*)d_in[5];
    const float* b2 = (const float*)d_in[6];
    const float* W3 = (const float*)d_in[7];
    const float* b3 = (const float*)d_in[8];
    const float* Wfc = (const float*)d_in[9];
    const float* bfc = (const float*)d_in[10];
    float* out = (float*)d_out;

    const int N = in_sizes[0] / 128;  // 100000
    const int E = in_sizes[1] / 2;    // 3200000
    const int G = out_size / 10;      // 512
    const int NB = (N + 127) / 128;   // 782
    const int chunk = (E + NBLK - 1) / NBLK;

    char* ws = (char*)d_ws;
    size_t off = 0;
    auto alloc = [&](size_t bytes) -> char* {
        char* p = ws + off;
        off = (off + bytes + 511) & ~(size_t)511;
        return p;
    };
    int* deg = (int*)alloc((size_t)N * 4);
    int* rowptr = (int*)alloc((size_t)N * 4);
    float* dis = (float*)alloc((size_t)N * 4);
    int* starts = (int*)alloc((size_t)(MAXNB + 1) * 4);
    int* btotal = (int*)alloc((size_t)MAXNB * 4);
    int* blockhist = (int*)alloc((size_t)NB * NBLK * 4);
    unsigned int* epart = (unsigned int*)alloc((size_t)E * 4);
    int* colidx = (int*)alloc((size_t)E * 4);
    unsigned short* hsb = (unsigned short*)alloc((size_t)N * 64 * 2);  // bf16
    float* obuf = (float*)alloc((size_t)N * 64 * 4);
    float* psum = (float*)alloc((size_t)G * 64 * 4 + (size_t)G * 4);
    float* pcnt = psum + (size_t)G * 64;

    hipMemsetAsync(psum, 0, (size_t)G * 64 * 4 + (size_t)G * 4, stream);

    const int* esrc = eidx;
    const int* edst = eidx + E;

    k_hist<<<NBLK, 256, 0, stream>>>(edst, blockhist, E, chunk, NB);
    k_bscan<<<NB, 256, 0, stream>>>(blockhist, btotal);
    k_sscan<<<1, 256, 0, stream>>>(btotal, starts, NB);
    k_part<<<NBLK, 256, 0, stream>>>(esrc, edst, blockhist, starts, epart, E, chunk, NB);
    k_fine<<<NB, 256, 0, stream>>>(epart, starts, deg, rowptr, dis, colidx, N);

    int gblk = (N + 63) / 64;
    k_gemm<128><<<gblk, 256, 0, stream>>>(x, W1, dis, hsb, N);
    k_agg<1><<<(N + 3) / 4, 256, 0, stream>>>(hsb, rowptr, deg, colidx, dis, b1, obuf, N);
    k_gemm<64><<<gblk, 256, 0, stream>>>(obuf, W2, dis, hsb, N);
    k_agg<1><<<(N + 3) / 4, 256, 0, stream>>>(hsb, rowptr, deg, colidx, dis, b2, obuf, N);
    k_gemm<64><<<gblk, 256, 0, stream>>>(obuf, W3, dis, hsb, N);
    k_agg<0><<<(N + 3) / 4, 256, 0, stream>>>(hsb, rowptr, deg, colidx, dis, b3, obuf, N);

    k_pool<<<(N + 63) / 64, 256, 0, stream>>>(obuf, batch, psum, pcnt, N);
    k_head<<<G, 64, 0, stream>>>(psum, pcnt, Wfc, bfc, out);
}